// Round 1
// baseline (3716.639 us; speedup 1.0000x reference)
//
#include <hip/hip_runtime.h>

// GraphSAGE 2-layer, fp32 baseline.
// inputs: 0:x[100000,128] 1:edge_index[2,625000] (int32) 2:W_l0[128,256]
//         3:W_r0[128,256] 4:b0[256] 5:W_l1[256,256] 6:W_r1[256,256] 7:b1[256]
// out: [100000,256] fp32

constexpr int NN   = 100000;
constexpr int NE   = 625000;
constexpr int DIN  = 128;
constexpr int DHID = 256;

// ---------------- scatter-add (mean aggregation numerator + counts) ----------
// One thread per (edge, 4-feature-group). float4 gather from src row,
// 4 scalar atomics into dst row. K4 = K/4.
template <int K4, bool COUNT>
__global__ __launch_bounds__(256) void scatter_add_kernel(
    const int* __restrict__ src, const int* __restrict__ dst,
    const float* __restrict__ feat, float* __restrict__ agg,
    float* __restrict__ cnt)
{
    int tid = blockIdx.x * 256 + threadIdx.x;
    constexpr int TOTAL = NE * K4;
    if (tid >= TOTAL) return;
    int e = tid / K4;            // constexpr K4 -> shift
    int k = tid - e * K4;
    int s = src[e];
    int d = dst[e];
    float4 v = reinterpret_cast<const float4*>(feat)[(size_t)s * K4 + k];
    float* o = agg + ((size_t)d * K4 + k) * 4;
    atomicAdd(o + 0, v.x);
    atomicAdd(o + 1, v.y);
    atomicAdd(o + 2, v.z);
    atomicAdd(o + 3, v.w);
    if (COUNT && k == 0) atomicAdd(cnt + d, 1.0f);
}

// ---------------- fused SAGE GEMM ---------------------------------------
// out[m, c] = relu( (agg[m,:]/max(cnt[m],1)) @ Wl + bias + x[m,:] @ Wr )
// Treated as one GEMM with A = [agg_norm | x]  (M x 2K), B = [Wl; Wr] (2K x 256).
// 64x64 output tile per block, 256 threads, 4x4 per thread, BK=16.
template <int K>
__global__ __launch_bounds__(256) void sage_fused_gemm(
    const float* __restrict__ agg, const float* __restrict__ cnt,
    const float* __restrict__ xr,
    const float* __restrict__ Wl, const float* __restrict__ Wr,
    const float* __restrict__ bias, float* __restrict__ out, int N)
{
    __shared__ float As[16][68];   // [kk][m], padded
    __shared__ float Bs[16][68];   // [kk][c], padded

    const int t  = threadIdx.x;
    const int tx = t & 15;         // col group
    const int ty = t >> 4;         // row group
    const int m0 = blockIdx.x * 64;
    const int c0 = blockIdx.y * 64;

    float acc[4][4] = {};

    // A-loader coords: each thread loads one float4 per K-tile
    const int am  = t >> 2;        // 0..63 row in tile
    const int akq = t & 3;         // 0..3  k-quad
    const int gm  = m0 + am;
    float rinv = 1.0f;
    if (gm < N) rinv = 1.0f / fmaxf(cnt[gm], 1.0f);

    // B-loader coords
    const int bk = t >> 4;         // 0..15
    const int bc = (t & 15) * 4;   // 0..60

    constexpr int KTILES = (2 * K) / 16;
    for (int kt = 0; kt < KTILES; ++kt) {
        // ---- load A tile (transposed store) ----
        float4 av = make_float4(0.f, 0.f, 0.f, 0.f);
        if (gm < N) {
            int kg = kt * 16 + akq * 4;
            if (kg < K) {
                av = *reinterpret_cast<const float4*>(&agg[(size_t)gm * K + kg]);
                av.x *= rinv; av.y *= rinv; av.z *= rinv; av.w *= rinv;
            } else {
                av = *reinterpret_cast<const float4*>(&xr[(size_t)gm * K + (kg - K)]);
            }
        }
        As[akq * 4 + 0][am] = av.x;
        As[akq * 4 + 1][am] = av.y;
        As[akq * 4 + 2][am] = av.z;
        As[akq * 4 + 3][am] = av.w;

        // ---- load B tile ----
        {
            int kg = kt * 16 + bk;
            const float* Bp = (kg < K) ? (Wl + (size_t)kg * DHID)
                                       : (Wr + (size_t)(kg - K) * DHID);
            float4 bv = *reinterpret_cast<const float4*>(&Bp[c0 + bc]);
            *reinterpret_cast<float4*>(&Bs[bk][bc]) = bv;
        }
        __syncthreads();

        // ---- FMA inner loop ----
        #pragma unroll
        for (int kk = 0; kk < 16; ++kk) {
            float4 a = *reinterpret_cast<const float4*>(&As[kk][ty * 4]);
            float4 b = *reinterpret_cast<const float4*>(&Bs[kk][tx * 4]);
            float af[4] = {a.x, a.y, a.z, a.w};
            float bf[4] = {b.x, b.y, b.z, b.w};
            #pragma unroll
            for (int i = 0; i < 4; ++i)
                #pragma unroll
                for (int j = 0; j < 4; ++j)
                    acc[i][j] += af[i] * bf[j];
        }
        __syncthreads();
    }

    // ---- epilogue: bias + relu, float4 store ----
    float4 b4 = *reinterpret_cast<const float4*>(&bias[c0 + tx * 4]);
    float bb[4] = {b4.x, b4.y, b4.z, b4.w};
    #pragma unroll
    for (int i = 0; i < 4; ++i) {
        int g = m0 + ty * 4 + i;
        if (g >= N) continue;
        float4 o;
        o.x = fmaxf(acc[i][0] + bb[0], 0.f);
        o.y = fmaxf(acc[i][1] + bb[1], 0.f);
        o.z = fmaxf(acc[i][2] + bb[2], 0.f);
        o.w = fmaxf(acc[i][3] + bb[3], 0.f);
        *reinterpret_cast<float4*>(&out[(size_t)g * DHID + c0 + tx * 4]) = o;
    }
}

extern "C" void kernel_launch(void* const* d_in, const int* in_sizes, int n_in,
                              void* d_out, int out_size, void* d_ws, size_t ws_size,
                              hipStream_t stream)
{
    const float* x   = (const float*)d_in[0];
    const int*   ei  = (const int*)d_in[1];
    const int*   src = ei;            // edge_index[0]
    const int*   dst = ei + NE;       // edge_index[1]
    const float* Wl0 = (const float*)d_in[2];
    const float* Wr0 = (const float*)d_in[3];
    const float* b0  = (const float*)d_in[4];
    const float* Wl1 = (const float*)d_in[5];
    const float* Wr1 = (const float*)d_in[6];
    const float* b1  = (const float*)d_in[7];
    float* out = (float*)d_out;

    // workspace layout (bytes), all 256B-aligned:
    //   cnt  : NN floats            @ 0
    //   agg0 : NN*DIN floats        @ 400384
    //   h0   : NN*DHID floats       @ 400384 + 51200000
    //   agg1 : NN*DHID floats       @ 400384 + 51200000 + 102400000
    // total ~256.4 MB
    char* ws = (char*)d_ws;
    float* cnt  = (float*)(ws);
    float* agg0 = (float*)(ws + 400384);
    float* h0   = (float*)(ws + 400384 + 51200000);
    float* agg1 = (float*)(ws + 400384 + 51200000 + 102400000);

    // zero accumulators every call (harness poisons ws once, never re-poisons)
    hipMemsetAsync(cnt,  0, (size_t)NN * sizeof(float), stream);
    hipMemsetAsync(agg0, 0, (size_t)NN * DIN * sizeof(float), stream);
    hipMemsetAsync(agg1, 0, (size_t)NN * DHID * sizeof(float), stream);

    // ---- layer 0 ----
    {
        constexpr int K4 = DIN / 4;             // 32
        int total = NE * K4;                    // 20M
        scatter_add_kernel<K4, true><<<(total + 255) / 256, 256, 0, stream>>>(
            src, dst, x, agg0, cnt);
        dim3 grid((NN + 63) / 64, DHID / 64);
        sage_fused_gemm<DIN><<<grid, 256, 0, stream>>>(
            agg0, cnt, x, Wl0, Wr0, b0, h0, NN);
    }

    // ---- layer 1 ----
    {
        constexpr int K4 = DHID / 4;            // 64
        int total = NE * K4;                    // 40M
        scatter_add_kernel<K4, false><<<(total + 255) / 256, 256, 0, stream>>>(
            src, dst, h0, agg1, nullptr);
        dim3 grid((NN + 63) / 64, DHID / 64);
        sage_fused_gemm<DHID><<<grid, 256, 0, stream>>>(
            agg1, cnt, h0, Wl1, Wr1, b1, out, NN);
    }
}

// Round 2
// 1119.349 us; speedup vs baseline: 3.3204x; 3.3204x over previous
//
#include <hip/hip_runtime.h>

// GraphSAGE 2-layer. CSR-gather aggregation (no feature atomics) + fused fp32 GEMM.
// inputs: 0:x[100000,128] 1:edge_index[2,625000] (int32) 2:W_l0[128,256]
//         3:W_r0[128,256] 4:b0[256] 5:W_l1[256,256] 6:W_r1[256,256] 7:b1[256]
// out: [100000,256] fp32

constexpr int NN   = 100000;
constexpr int NE   = 625000;
constexpr int DIN  = 128;
constexpr int DHID = 256;

// ---------------- CSR build ------------------------------------------------
__global__ __launch_bounds__(256) void hist_kernel(const int* __restrict__ dst,
                                                   int* __restrict__ hist)
{
    int t = blockIdx.x * 256 + threadIdx.x;
    if (t < NE) atomicAdd(&hist[dst[t]], 1);
}

// Single-block exclusive scan of hist[0..NN) -> offs; hist becomes cursor(=offs copy).
__global__ __launch_bounds__(1024) void scan_kernel(int* __restrict__ hist,
                                                    int* __restrict__ offs)
{
    __shared__ int sums[1024];
    const int t = threadIdx.x;
    constexpr int CH = (NN + 1023) / 1024;   // 98
    int lo = t * CH;
    int hi = lo + CH; if (hi > NN) hi = NN;
    int s = 0;
    for (int i = lo; i < hi; ++i) s += hist[i];
    sums[t] = s;
    __syncthreads();
    for (int off = 1; off < 1024; off <<= 1) {
        int v = (t >= off) ? sums[t - off] : 0;
        __syncthreads();
        sums[t] += v;
        __syncthreads();
    }
    int run = (t == 0) ? 0 : sums[t - 1];
    for (int i = lo; i < hi; ++i) {
        int v = hist[i];
        offs[i] = run;
        hist[i] = run;      // cursor for perm_kernel
        run += v;
    }
    if (t == 1023) offs[NN] = NE;
}

__global__ __launch_bounds__(256) void perm_kernel(const int* __restrict__ src,
                                                   const int* __restrict__ dst,
                                                   int* __restrict__ cursor,
                                                   int* __restrict__ perm)
{
    int t = blockIdx.x * 256 + threadIdx.x;
    if (t < NE) {
        int p = atomicAdd(&cursor[dst[t]], 1);
        perm[p] = src[t];
    }
}

// ---------------- gather-mean aggregation ---------------------------------
// One wave per destination node. Lane l holds features [l*V, l*V+V).
template <int D>
__global__ __launch_bounds__(256) void gather_mean_kernel(
    const int* __restrict__ offs, const int* __restrict__ perm,
    const float* __restrict__ feat, float* __restrict__ agg)
{
    int w    = (blockIdx.x * 256 + threadIdx.x) >> 6;
    int lane = threadIdx.x & 63;
    if (w >= NN) return;
    int beg = offs[w], end = offs[w + 1];
    float sc = 1.0f / (float)((end - beg) > 1 ? (end - beg) : 1);
    if constexpr (D == 256) {
        const float4* base = reinterpret_cast<const float4*>(feat);
        float4 acc = make_float4(0.f, 0.f, 0.f, 0.f);
        for (int e = beg; e < end; ++e) {
            int s = perm[e];
            float4 v = base[(size_t)s * 64 + lane];
            acc.x += v.x; acc.y += v.y; acc.z += v.z; acc.w += v.w;
        }
        reinterpret_cast<float4*>(agg)[(size_t)w * 64 + lane] =
            make_float4(acc.x * sc, acc.y * sc, acc.z * sc, acc.w * sc);
    } else {             // D == 128
        const float2* base = reinterpret_cast<const float2*>(feat);
        float2 acc = make_float2(0.f, 0.f);
        for (int e = beg; e < end; ++e) {
            int s = perm[e];
            float2 v = base[(size_t)s * 64 + lane];
            acc.x += v.x; acc.y += v.y;
        }
        reinterpret_cast<float2*>(agg)[(size_t)w * 64 + lane] =
            make_float2(acc.x * sc, acc.y * sc);
    }
}

// ---------------- fused SAGE GEMM ------------------------------------------
// out[m, c] = relu( agg[m,:] @ Wl + bias + x[m,:] @ Wr )   (agg pre-normalized)
// A = [agg | x] (M x 2K), B = [Wl; Wr] (2K x 256). 64x64 tile, 4x4/thread.
template <int K>
__global__ __launch_bounds__(256) void sage_fused_gemm(
    const float* __restrict__ agg, const float* __restrict__ xr,
    const float* __restrict__ Wl, const float* __restrict__ Wr,
    const float* __restrict__ bias, float* __restrict__ out, int N)
{
    __shared__ float As[16][68];
    __shared__ float Bs[16][68];

    const int t  = threadIdx.x;
    const int tx = t & 15;
    const int ty = t >> 4;
    const int m0 = blockIdx.x * 64;
    const int c0 = blockIdx.y * 64;

    float acc[4][4] = {};

    const int am  = t >> 2;
    const int akq = t & 3;
    const int gm  = m0 + am;

    const int bk = t >> 4;
    const int bc = (t & 15) * 4;

    constexpr int KTILES = (2 * K) / 16;
    for (int kt = 0; kt < KTILES; ++kt) {
        float4 av = make_float4(0.f, 0.f, 0.f, 0.f);
        if (gm < N) {
            int kg = kt * 16 + akq * 4;
            if (kg < K) {
                av = *reinterpret_cast<const float4*>(&agg[(size_t)gm * K + kg]);
            } else {
                av = *reinterpret_cast<const float4*>(&xr[(size_t)gm * K + (kg - K)]);
            }
        }
        As[akq * 4 + 0][am] = av.x;
        As[akq * 4 + 1][am] = av.y;
        As[akq * 4 + 2][am] = av.z;
        As[akq * 4 + 3][am] = av.w;

        {
            int kg = kt * 16 + bk;
            const float* Bp = (kg < K) ? (Wl + (size_t)kg * DHID)
                                       : (Wr + (size_t)(kg - K) * DHID);
            float4 bv = *reinterpret_cast<const float4*>(&Bp[c0 + bc]);
            *reinterpret_cast<float4*>(&Bs[bk][bc]) = bv;
        }
        __syncthreads();

        #pragma unroll
        for (int kk = 0; kk < 16; ++kk) {
            float4 a = *reinterpret_cast<const float4*>(&As[kk][ty * 4]);
            float4 b = *reinterpret_cast<const float4*>(&Bs[kk][tx * 4]);
            float af[4] = {a.x, a.y, a.z, a.w};
            float bf[4] = {b.x, b.y, b.z, b.w};
            #pragma unroll
            for (int i = 0; i < 4; ++i)
                #pragma unroll
                for (int j = 0; j < 4; ++j)
                    acc[i][j] += af[i] * bf[j];
        }
        __syncthreads();
    }

    float4 b4 = *reinterpret_cast<const float4*>(&bias[c0 + tx * 4]);
    float bb[4] = {b4.x, b4.y, b4.z, b4.w};
    #pragma unroll
    for (int i = 0; i < 4; ++i) {
        int g = m0 + ty * 4 + i;
        if (g >= N) continue;
        float4 o;
        o.x = fmaxf(acc[i][0] + bb[0], 0.f);
        o.y = fmaxf(acc[i][1] + bb[1], 0.f);
        o.z = fmaxf(acc[i][2] + bb[2], 0.f);
        o.w = fmaxf(acc[i][3] + bb[3], 0.f);
        *reinterpret_cast<float4*>(&out[(size_t)g * DHID + c0 + tx * 4]) = o;
    }
}

extern "C" void kernel_launch(void* const* d_in, const int* in_sizes, int n_in,
                              void* d_out, int out_size, void* d_ws, size_t ws_size,
                              hipStream_t stream)
{
    const float* x   = (const float*)d_in[0];
    const int*   ei  = (const int*)d_in[1];
    const int*   src = ei;            // edge_index[0]
    const int*   dst = ei + NE;       // edge_index[1]
    const float* Wl0 = (const float*)d_in[2];
    const float* Wr0 = (const float*)d_in[3];
    const float* b0  = (const float*)d_in[4];
    const float* Wl1 = (const float*)d_in[5];
    const float* Wr1 = (const float*)d_in[6];
    const float* b1  = (const float*)d_in[7];
    float* out = (float*)d_out;

    // workspace layout (bytes):
    //   hist/cursor : NN int      @ 0           (400384)
    //   offs        : NN+1 int    @ 400384      (400640)
    //   perm        : NE int      @ 801024      (2500096)
    //   agg1        : NN*DHID f32 @ 3301376     (102400000)  [agg0 aliases 1st half]
    //   h0          : NN*DHID f32 @ 105701376   (102400000)
    // total 208.1 MB (round-0 proved >= 256.4 MB available)
    char* ws = (char*)d_ws;
    int*   hist = (int*)(ws);
    int*   offs = (int*)(ws + 400384);
    int*   perm = (int*)(ws + 801024);
    float* agg  = (float*)(ws + 3301376);          // agg0 and agg1 share this
    float* h0   = (float*)(ws + 105701376);

    hipMemsetAsync(hist, 0, (size_t)NN * sizeof(int), stream);

    hist_kernel<<<(NE + 255) / 256, 256, 0, stream>>>(dst, hist);
    scan_kernel<<<1, 1024, 0, stream>>>(hist, offs);
    perm_kernel<<<(NE + 255) / 256, 256, 0, stream>>>(src, dst, hist, perm);

    constexpr int NWBLK = (NN * 64 + 255) / 256;   // one wave per node, 4 waves/block

    // ---- layer 0 ----
    gather_mean_kernel<DIN><<<NWBLK, 256, 0, stream>>>(offs, perm, x, agg);
    {
        dim3 grid((NN + 63) / 64, DHID / 64);
        sage_fused_gemm<DIN><<<grid, 256, 0, stream>>>(agg, x, Wl0, Wr0, b0, h0, NN);
    }

    // ---- layer 1 ----
    gather_mean_kernel<DHID><<<NWBLK, 256, 0, stream>>>(offs, perm, h0, agg);
    {
        dim3 grid((NN + 63) / 64, DHID / 64);
        sage_fused_gemm<DHID><<<grid, 256, 0, stream>>>(agg, h0, Wl1, Wr1, b1, out, NN);
    }
}

// Round 4
// 566.120 us; speedup vs baseline: 6.5651x; 1.9772x over previous
//
#include <hip/hip_runtime.h>

// GraphSAGE 2-layer: CSR gather-mean (bf16 features) + bf16 MFMA fused GEMMs.
// inputs: 0:x[100000,128] 1:edge_index[2,625000] 2:W_l0[128,256] 3:W_r0[128,256]
//         4:b0[256] 5:W_l1[256,256] 6:W_r1[256,256] 7:b1[256]
// out: [100000,256] fp32
// R3 fix: gather_mean<128> row stride was 32 uints; a 128-bf16 row is 64 uints.

constexpr int NN   = 100000;
constexpr int NE   = 625000;
constexpr int DIN  = 128;
constexpr int DHID = 256;

using short8 = __attribute__((ext_vector_type(8))) short;
using f32x4  = __attribute__((ext_vector_type(4))) float;

__device__ __forceinline__ float bf2f(unsigned int u) {
    return __uint_as_float(u << 16);
}
__device__ __forceinline__ unsigned short f2b(float f) {
    unsigned int u = __float_as_uint(f);
    unsigned int r = (u + 0x7fffu + ((u >> 16) & 1u)) >> 16;   // RNE
    return (unsigned short)r;
}
__device__ __forceinline__ unsigned int pack2(float lo, float hi) {
    return (unsigned int)f2b(lo) | ((unsigned int)f2b(hi) << 16);
}
__device__ __forceinline__ void gload16(const void* g, void* lds) {
    __builtin_amdgcn_global_load_lds(
        (const __attribute__((address_space(1))) void*)g,
        (__attribute__((address_space(3))) void*)lds, 16, 0, 0);
}

// ---------------- CSR build ------------------------------------------------
__global__ __launch_bounds__(256) void hist_kernel(const int* __restrict__ dst,
                                                   int* __restrict__ hist)
{
    int t = blockIdx.x * 256 + threadIdx.x;
    if (t < NE) atomicAdd(&hist[dst[t]], 1);
}

__global__ __launch_bounds__(1024) void scan_kernel(int* __restrict__ hist,
                                                    int* __restrict__ offs)
{
    __shared__ int sums[1024];
    const int t = threadIdx.x;
    constexpr int CH = (NN + 1023) / 1024;
    int lo = t * CH;
    int hi = lo + CH; if (hi > NN) hi = NN;
    int s = 0;
    for (int i = lo; i < hi; ++i) s += hist[i];
    sums[t] = s;
    __syncthreads();
    for (int off = 1; off < 1024; off <<= 1) {
        int v = (t >= off) ? sums[t - off] : 0;
        __syncthreads();
        sums[t] += v;
        __syncthreads();
    }
    int run = (t == 0) ? 0 : sums[t - 1];
    for (int i = lo; i < hi; ++i) {
        int v = hist[i];
        offs[i] = run;
        hist[i] = run;      // cursor for perm_kernel
        run += v;
    }
    if (t == 1023) offs[NN] = NE;
}

__global__ __launch_bounds__(256) void perm_kernel(const int* __restrict__ src,
                                                   const int* __restrict__ dst,
                                                   int* __restrict__ cursor,
                                                   int* __restrict__ perm)
{
    int t = blockIdx.x * 256 + threadIdx.x;
    if (t < NE) {
        int p = atomicAdd(&cursor[dst[t]], 1);
        perm[p] = src[t];
    }
}

// ---------------- fp32 -> bf16 convert (x) ---------------------------------
__global__ __launch_bounds__(256) void convert_kernel(const float* __restrict__ in,
                                                      unsigned short* __restrict__ outb,
                                                      int n8)
{
    int t = blockIdx.x * 256 + threadIdx.x;
    if (t >= n8) return;
    float4 v0 = reinterpret_cast<const float4*>(in)[t * 2 + 0];
    float4 v1 = reinterpret_cast<const float4*>(in)[t * 2 + 1];
    uint4 o;
    o.x = pack2(v0.x, v0.y); o.y = pack2(v0.z, v0.w);
    o.z = pack2(v1.x, v1.y); o.w = pack2(v1.z, v1.w);
    reinterpret_cast<uint4*>(outb)[t] = o;
}

// ---------------- weight prep: WT[n][k] = concat(Wl,Wr)^T, bf16 ------------
template <int KP>
__global__ __launch_bounds__(256) void prep_w_kernel(const float* __restrict__ Wl,
                                                     const float* __restrict__ Wr,
                                                     unsigned short* __restrict__ WT)
{
    int t = blockIdx.x * 256 + threadIdx.x;
    constexpr int K2 = 2 * KP;
    if (t >= 256 * K2) return;
    int n = t / K2;
    int k = t - n * K2;
    float v = (k < KP) ? Wl[(size_t)k * DHID + n] : Wr[(size_t)(k - KP) * DHID + n];
    WT[t] = f2b(v);
}

// ---------------- gather-mean aggregation (bf16 in/out, fp32 accum) --------
template <int D>
__global__ __launch_bounds__(256) void gather_mean_kernel(
    const int* __restrict__ offs, const int* __restrict__ perm,
    const unsigned short* __restrict__ feat, unsigned short* __restrict__ agg)
{
    int w    = (blockIdx.x * 256 + threadIdx.x) >> 6;
    int lane = threadIdx.x & 63;
    if (w >= NN) return;
    int beg = offs[w], end = offs[w + 1];
    int n = end - beg;
    float sc = 1.0f / (float)(n > 1 ? n : 1);
    if constexpr (D == 256) {
        // row = 256 bf16 = 64 x uint2
        float a0 = 0, a1 = 0, a2 = 0, a3 = 0;
        for (int e = beg; e < end; ++e) {
            int s = perm[e];
            uint2 v = reinterpret_cast<const uint2*>(feat)[(size_t)s * 64 + lane];
            a0 += bf2f(v.x & 0xffffu); a1 += bf2f(v.x >> 16);
            a2 += bf2f(v.y & 0xffffu); a3 += bf2f(v.y >> 16);
        }
        uint2 o;
        o.x = pack2(a0 * sc, a1 * sc);
        o.y = pack2(a2 * sc, a3 * sc);
        reinterpret_cast<uint2*>(agg)[(size_t)w * 64 + lane] = o;
    } else {   // D == 128: row = 128 bf16 = 64 x uint
        float a0 = 0, a1 = 0;
        for (int e = beg; e < end; ++e) {
            int s = perm[e];
            unsigned int v = reinterpret_cast<const unsigned int*>(feat)[(size_t)s * 64 + lane];
            a0 += bf2f(v & 0xffffu); a1 += bf2f(v >> 16);
        }
        reinterpret_cast<unsigned int*>(agg)[(size_t)w * 64 + lane] = pack2(a0 * sc, a1 * sc);
    }
}

// ---------------- bf16 MFMA fused SAGE GEMM --------------------------------
// out[m,c] = relu( [agg | xr][m,:] @ WT^T + bias ),  WT is [256][2KP] bf16.
// 128x128 tile, 4 waves (2x2 of 64x64), BK=32, 16x16x32 MFMA.
// LDS tiles stored with XOR swizzle: chunk c16' = c16 ^ (row&3) (16B chunks),
// applied on BOTH the global_load_lds source address and the ds_read address.
template <int KP, bool WF, bool WB>
__global__ __launch_bounds__(256) void sage_mfma_gemm(
    const unsigned short* __restrict__ Aagg,  // [M, KP] bf16
    const unsigned short* __restrict__ Axr,   // [M, KP] bf16
    const unsigned short* __restrict__ WT,    // [256, 2KP] bf16
    const float* __restrict__ bias,
    float* __restrict__ outf,                 // used if WF
    unsigned short* __restrict__ outb,        // used if WB
    int M)
{
    __shared__ __align__(16) unsigned short As[128 * 32];
    __shared__ __align__(16) unsigned short Bs[128 * 32];

    const int t   = threadIdx.x;
    const int l   = t & 63;
    const int wid = t >> 6;
    const int wr  = wid >> 1, wc = wid & 1;
    const int m0  = blockIdx.x * 128;
    const int c0  = blockIdx.y * 128;

    // staging coords: this wave stages chunks 2*wid, 2*wid+1 (16 rows each)
    const int rin = l >> 2;                  // row within chunk
    const int p   = l & 3;                   // physical 16B slot in row
    const int csw = p ^ (rin & 3);           // swizzled source chunk
    const int ch0 = wid * 2, ch1 = ch0 + 1;

    int arow0 = m0 + ch0 * 16 + rin; if (arow0 >= M) arow0 = M - 1;
    int arow1 = m0 + ch1 * 16 + rin; if (arow1 >= M) arow1 = M - 1;
    const int brow0 = c0 + ch0 * 16 + rin;
    const int brow1 = c0 + ch1 * 16 + rin;

    unsigned short* AsD0 = As + ch0 * 512;   // wave-uniform LDS dest (1KB chunk)
    unsigned short* AsD1 = As + ch1 * 512;
    unsigned short* BsD0 = Bs + ch0 * 512;
    unsigned short* BsD1 = Bs + ch1 * 512;

    // fragment-read bases (XOR swizzle on read side): row = ...+ (l&15),
    // byte = row*64 + ((l>>4) ^ (row&3))*16 ; note row&3 == l&3.
    const int fr  = l & 15;
    const int swz = ((l >> 4) ^ (l & 3)) * 8;           // ushort units
    const unsigned short* ArdB = As + (wr * 64 + fr) * 32 + swz;
    const unsigned short* BrdB = Bs + (wc * 64 + fr) * 32 + swz;

    f32x4 acc[4][4] = {};

    constexpr int K2 = 2 * KP;
    constexpr int KT = K2 / 32;
    for (int kt = 0; kt < KT; ++kt) {
        const int kb = kt * 32;
        const unsigned short* Asrc;
        int kk;
        if (kb < KP) { Asrc = Aagg; kk = kb; }
        else         { Asrc = Axr;  kk = kb - KP; }
        gload16(Asrc + (size_t)arow0 * KP + kk + csw * 8, AsD0);
        gload16(Asrc + (size_t)arow1 * KP + kk + csw * 8, AsD1);
        gload16(WT + (size_t)brow0 * K2 + kb + csw * 8, BsD0);
        gload16(WT + (size_t)brow1 * K2 + kb + csw * 8, BsD1);
        __syncthreads();   // drains vmcnt (gload_lds) per compiler semantics

        short8 af[4], bf[4];
        #pragma unroll
        for (int i = 0; i < 4; ++i)
            af[i] = *reinterpret_cast<const short8*>(ArdB + i * 512);
        #pragma unroll
        for (int i = 0; i < 4; ++i)
            bf[i] = *reinterpret_cast<const short8*>(BrdB + i * 512);
        #pragma unroll
        for (int i = 0; i < 4; ++i)
            #pragma unroll
            for (int j = 0; j < 4; ++j)
                acc[i][j] = __builtin_amdgcn_mfma_f32_16x16x32_bf16(
                    af[i], bf[j], acc[i][j], 0, 0, 0);
        __syncthreads();
    }

    // epilogue: C/D layout col = l&15, row = (l>>4)*4 + reg
    const int rq = (l >> 4) * 4;
    #pragma unroll
    for (int fn = 0; fn < 4; ++fn) {
        const int col = c0 + wc * 64 + fn * 16 + fr;
        const float bb = bias[col];
        #pragma unroll
        for (int fm = 0; fm < 4; ++fm) {
            const int rbase = m0 + wr * 64 + fm * 16 + rq;
            #pragma unroll
            for (int j = 0; j < 4; ++j) {
                const int r = rbase + j;
                if (r < M) {
                    float v = fmaxf(acc[fm][fn][j] + bb, 0.f);
                    if (WF) outf[(size_t)r * DHID + col] = v;
                    if (WB) outb[(size_t)r * DHID + col] = f2b(v);
                }
            }
        }
    }
}

extern "C" void kernel_launch(void* const* d_in, const int* in_sizes, int n_in,
                              void* d_out, int out_size, void* d_ws, size_t ws_size,
                              hipStream_t stream)
{
    const float* x   = (const float*)d_in[0];
    const int*   ei  = (const int*)d_in[1];
    const int*   src = ei;
    const int*   dst = ei + NE;
    const float* Wl0 = (const float*)d_in[2];
    const float* Wr0 = (const float*)d_in[3];
    const float* b0  = (const float*)d_in[4];
    const float* Wl1 = (const float*)d_in[5];
    const float* Wr1 = (const float*)d_in[6];
    const float* b1  = (const float*)d_in[7];
    float* out = (float*)d_out;

    // workspace layout (bytes):
    //   hist/cursor : @0         400384
    //   offs        : @400384    400640
    //   perm        : @801024    2500352
    //   WT0         : @3301376   131072   (256 x 256 bf16)
    //   WT1         : @3432448   262144   (256 x 512 bf16)
    //   xb          : @3694592   25600000 (100000 x 128 bf16)
    //   h0b         : @29294592  51200000 (100000 x 256 bf16)
    //   aggb        : @80494592  51200000 (100000 x 256 bf16; L0 uses half)
    // total ~131.7 MB (round-0 proved >=256 MB available)
    char* ws = (char*)d_ws;
    int*            hist = (int*)(ws);
    int*            offs = (int*)(ws + 400384);
    int*            perm = (int*)(ws + 801024);
    unsigned short* WT0  = (unsigned short*)(ws + 3301376);
    unsigned short* WT1  = (unsigned short*)(ws + 3432448);
    unsigned short* xb   = (unsigned short*)(ws + 3694592);
    unsigned short* h0b  = (unsigned short*)(ws + 29294592);
    unsigned short* aggb = (unsigned short*)(ws + 80494592);

    hipMemsetAsync(hist, 0, (size_t)NN * sizeof(int), stream);

    hist_kernel<<<(NE + 255) / 256, 256, 0, stream>>>(dst, hist);
    scan_kernel<<<1, 1024, 0, stream>>>(hist, offs);
    perm_kernel<<<(NE + 255) / 256, 256, 0, stream>>>(src, dst, hist, perm);

    // weight prep + x conversion (independent of CSR)
    prep_w_kernel<DIN ><<<(256 * 2 * DIN  + 255) / 256, 256, 0, stream>>>(Wl0, Wr0, WT0);
    prep_w_kernel<DHID><<<(256 * 2 * DHID + 255) / 256, 256, 0, stream>>>(Wl1, Wr1, WT1);
    convert_kernel<<<(NN * DIN / 8 + 255) / 256, 256, 0, stream>>>(x, xb, NN * DIN / 8);

    constexpr int NWBLK = (NN * 64 + 255) / 256;
    dim3 ggrid((NN + 127) / 128, DHID / 128);

    // ---- layer 0 ----
    gather_mean_kernel<DIN><<<NWBLK, 256, 0, stream>>>(offs, perm, xb, aggb);
    sage_mfma_gemm<DIN, false, true><<<ggrid, 256, 0, stream>>>(
        aggb, xb, WT0, b0, nullptr, h0b, NN);

    // ---- layer 1 ----
    gather_mean_kernel<DHID><<<NWBLK, 256, 0, stream>>>(offs, perm, h0b, aggb);
    sage_mfma_gemm<DHID, true, false><<<ggrid, 256, 0, stream>>>(
        aggb, h0b, WT1, b1, out, nullptr, NN);
}

// Round 6
// 352.419 us; speedup vs baseline: 10.5461x; 1.6064x over previous
//
#include <hip/hip_runtime.h>

// GraphSAGE 2-layer: CSR gather-mean (bf16 features) + bf16 MFMA fused GEMMs.
// R6 hedges vs R5 replay-divergence: no memset node in graph (zero_kernel),
// separate cursor buffer (offs/hist never mutated after write), explicit
// vmcnt(0) before the GEMM K-loop barrier.

constexpr int NN   = 100000;
constexpr int NE   = 625000;
constexpr int DIN  = 128;
constexpr int DHID = 256;
constexpr int NB   = (NN + 255) / 256;     // 391 scan chunks

using short8 = __attribute__((ext_vector_type(8))) short;
using f32x4  = __attribute__((ext_vector_type(4))) float;

__device__ __forceinline__ float bf2f(unsigned int u) {
    return __uint_as_float(u << 16);
}
__device__ __forceinline__ unsigned short f2b(float f) {
    unsigned int u = __float_as_uint(f);
    unsigned int r = (u + 0x7fffu + ((u >> 16) & 1u)) >> 16;   // RNE
    return (unsigned short)r;
}
__device__ __forceinline__ unsigned int pack2(float lo, float hi) {
    return (unsigned int)f2b(lo) | ((unsigned int)f2b(hi) << 16);
}
__device__ __forceinline__ void gload16(const void* g, void* lds) {
    __builtin_amdgcn_global_load_lds(
        (const __attribute__((address_space(1))) void*)g,
        (__attribute__((address_space(3))) void*)lds, 16, 0, 0);
}

// ---------------- CSR build ------------------------------------------------
__global__ __launch_bounds__(256) void zero_kernel(int* __restrict__ p, int n)
{
    int t = blockIdx.x * 256 + threadIdx.x;
    if (t < n) p[t] = 0;
}

__global__ __launch_bounds__(256) void hist_kernel(const int* __restrict__ dst,
                                                   int* __restrict__ hist)
{
    int t = blockIdx.x * 256 + threadIdx.x;
    if (t < NE) atomicAdd(&hist[dst[t]], 1);
}

// (1) per-256-chunk sums
__global__ __launch_bounds__(256) void chunk_sum_kernel(const int* __restrict__ hist,
                                                        int* __restrict__ bsum)
{
    __shared__ int s[256];
    int i = blockIdx.x * 256 + threadIdx.x;
    s[threadIdx.x] = (i < NN) ? hist[i] : 0;
    __syncthreads();
    for (int off = 128; off > 0; off >>= 1) {
        if (threadIdx.x < off) s[threadIdx.x] += s[threadIdx.x + off];
        __syncthreads();
    }
    if (threadIdx.x == 0) bsum[blockIdx.x] = s[0];
}

// (2) scan the 391 chunk sums (single small block)
__global__ __launch_bounds__(512) void scan_bsum_kernel(const int* __restrict__ bsum,
                                                        int* __restrict__ bpre)
{
    __shared__ int s[512];
    int t = threadIdx.x;
    int v = (t < NB) ? bsum[t] : 0;
    s[t] = v;
    __syncthreads();
    for (int off = 1; off < 512; off <<= 1) {
        int u = (t >= off) ? s[t - off] : 0;
        __syncthreads();
        s[t] += u;
        __syncthreads();
    }
    if (t < NB) bpre[t] = s[t] - v;        // exclusive prefix
}

// (3) per-chunk exclusive scan + chunk offset -> offs[] and cursor[]
__global__ __launch_bounds__(256) void scatter_offs_kernel(const int* __restrict__ hist,
                                                           const int* __restrict__ bpre,
                                                           int* __restrict__ offs,
                                                           int* __restrict__ cursor)
{
    __shared__ int s[256];
    int t = threadIdx.x;
    int i = blockIdx.x * 256 + t;
    int v = (i < NN) ? hist[i] : 0;
    s[t] = v;
    __syncthreads();
    for (int off = 1; off < 256; off <<= 1) {
        int u = (t >= off) ? s[t - off] : 0;
        __syncthreads();
        s[t] += u;
        __syncthreads();
    }
    int excl = s[t] - v + bpre[blockIdx.x];
    if (i < NN) {
        offs[i]   = excl;
        cursor[i] = excl;
    }
    if (i == NN - 1) offs[NN] = NE;
}

__global__ __launch_bounds__(256) void perm_kernel(const int* __restrict__ src,
                                                   const int* __restrict__ dst,
                                                   int* __restrict__ cursor,
                                                   int* __restrict__ perm)
{
    int t = blockIdx.x * 256 + threadIdx.x;
    if (t < NE) {
        int p = atomicAdd(&cursor[dst[t]], 1);
        perm[p] = src[t];
    }
}

// ---------------- fp32 -> bf16 convert (x) ---------------------------------
__global__ __launch_bounds__(256) void convert_kernel(const float* __restrict__ in,
                                                      unsigned short* __restrict__ outb,
                                                      int n8)
{
    int t = blockIdx.x * 256 + threadIdx.x;
    if (t >= n8) return;
    float4 v0 = reinterpret_cast<const float4*>(in)[t * 2 + 0];
    float4 v1 = reinterpret_cast<const float4*>(in)[t * 2 + 1];
    uint4 o;
    o.x = pack2(v0.x, v0.y); o.y = pack2(v0.z, v0.w);
    o.z = pack2(v1.x, v1.y); o.w = pack2(v1.z, v1.w);
    reinterpret_cast<uint4*>(outb)[t] = o;
}

// ---------------- weight prep: WT[n][k] = concat(Wl,Wr)^T, bf16 ------------
template <int KP>
__global__ __launch_bounds__(256) void prep_w_kernel(const float* __restrict__ Wl,
                                                     const float* __restrict__ Wr,
                                                     unsigned short* __restrict__ WT)
{
    int t = blockIdx.x * 256 + threadIdx.x;
    constexpr int K2 = 2 * KP;
    if (t >= 256 * K2) return;
    int n = t / K2;
    int k = t - n * K2;
    float v = (k < KP) ? Wl[(size_t)k * DHID + n] : Wr[(size_t)(k - KP) * DHID + n];
    WT[t] = f2b(v);
}

// ---------------- gather-mean aggregation (bf16 in/out, fp32 accum) --------
template <int D>
__global__ __launch_bounds__(256) void gather_mean_kernel(
    const int* __restrict__ offs, const int* __restrict__ perm,
    const unsigned short* __restrict__ feat, unsigned short* __restrict__ agg)
{
    int w    = (blockIdx.x * 256 + threadIdx.x) >> 6;
    int lane = threadIdx.x & 63;
    if (w >= NN) return;
    int beg = offs[w], end = offs[w + 1];
    int n = end - beg;
    float sc = 1.0f / (float)(n > 1 ? n : 1);
    if constexpr (D == 256) {
        // row = 256 bf16 = 64 x uint2
        float a0 = 0, a1 = 0, a2 = 0, a3 = 0;
        for (int e = beg; e < end; ++e) {
            int s = perm[e];
            uint2 v = reinterpret_cast<const uint2*>(feat)[(size_t)s * 64 + lane];
            a0 += bf2f(v.x & 0xffffu); a1 += bf2f(v.x >> 16);
            a2 += bf2f(v.y & 0xffffu); a3 += bf2f(v.y >> 16);
        }
        uint2 o;
        o.x = pack2(a0 * sc, a1 * sc);
        o.y = pack2(a2 * sc, a3 * sc);
        reinterpret_cast<uint2*>(agg)[(size_t)w * 64 + lane] = o;
    } else {   // D == 128: row = 128 bf16 = 64 x uint
        float a0 = 0, a1 = 0;
        for (int e = beg; e < end; ++e) {
            int s = perm[e];
            unsigned int v = reinterpret_cast<const unsigned int*>(feat)[(size_t)s * 64 + lane];
            a0 += bf2f(v & 0xffffu); a1 += bf2f(v >> 16);
        }
        reinterpret_cast<unsigned int*>(agg)[(size_t)w * 64 + lane] = pack2(a0 * sc, a1 * sc);
    }
}

// ---------------- bf16 MFMA fused SAGE GEMM --------------------------------
// out[m,c] = relu( [agg | xr][m,:] @ WT^T + bias ),  WT is [256][2KP] bf16.
// 128x128 tile, 4 waves (2x2 of 64x64), BK=32, 16x16x32 MFMA.
// LDS swizzle: chunk c16' = c16 ^ (row&3), applied on BOTH gload source and
// ds_read address (rule #21: both-sides-or-neither).
template <int KP, bool WF, bool WB>
__global__ __launch_bounds__(256) void sage_mfma_gemm(
    const unsigned short* __restrict__ Aagg,  // [M, KP] bf16
    const unsigned short* __restrict__ Axr,   // [M, KP] bf16
    const unsigned short* __restrict__ WT,    // [256, 2KP] bf16
    const float* __restrict__ bias,
    float* __restrict__ outf,                 // used if WF
    unsigned short* __restrict__ outb,        // used if WB
    int M)
{
    __shared__ __align__(16) unsigned short As[128 * 32];
    __shared__ __align__(16) unsigned short Bs[128 * 32];

    const int t   = threadIdx.x;
    const int l   = t & 63;
    const int wid = t >> 6;
    const int wr  = wid >> 1, wc = wid & 1;
    const int m0  = blockIdx.x * 128;
    const int c0  = blockIdx.y * 128;

    // staging coords: this wave stages chunks 2*wid, 2*wid+1 (16 rows each)
    const int rin = l >> 2;                  // row within chunk
    const int p   = l & 3;                   // physical 16B slot in row
    const int csw = p ^ (rin & 3);           // swizzled source chunk
    const int ch0 = wid * 2, ch1 = ch0 + 1;

    int arow0 = m0 + ch0 * 16 + rin; if (arow0 >= M) arow0 = M - 1;
    int arow1 = m0 + ch1 * 16 + rin; if (arow1 >= M) arow1 = M - 1;
    const int brow0 = c0 + ch0 * 16 + rin;
    const int brow1 = c0 + ch1 * 16 + rin;

    unsigned short* AsD0 = As + ch0 * 512;   // wave-uniform LDS dest (1KB chunk)
    unsigned short* AsD1 = As + ch1 * 512;
    unsigned short* BsD0 = Bs + ch0 * 512;
    unsigned short* BsD1 = Bs + ch1 * 512;

    // fragment-read bases: row = ...+(l&15), slot = (l>>4) ^ (row&3)
    const int fr  = l & 15;
    const int swz = ((l >> 4) ^ (l & 3)) * 8;           // ushort units
    const unsigned short* ArdB = As + (wr * 64 + fr) * 32 + swz;
    const unsigned short* BrdB = Bs + (wc * 64 + fr) * 32 + swz;

    f32x4 acc[4][4] = {};

    constexpr int K2 = 2 * KP;
    constexpr int KT = K2 / 32;
    for (int kt = 0; kt < KT; ++kt) {
        const int kb = kt * 32;
        const unsigned short* Asrc;
        int kk;
        if (kb < KP) { Asrc = Aagg; kk = kb; }
        else         { Asrc = Axr;  kk = kb - KP; }
        gload16(Asrc + (size_t)arow0 * KP + kk + csw * 8, AsD0);
        gload16(Asrc + (size_t)arow1 * KP + kk + csw * 8, AsD1);
        gload16(WT + (size_t)brow0 * K2 + kb + csw * 8, BsD0);
        gload16(WT + (size_t)brow1 * K2 + kb + csw * 8, BsD1);
        asm volatile("s_waitcnt vmcnt(0)" ::: "memory");  // explicit drain
        __syncthreads();

        short8 af[4], bf[4];
        #pragma unroll
        for (int i = 0; i < 4; ++i)
            af[i] = *reinterpret_cast<const short8*>(ArdB + i * 512);
        #pragma unroll
        for (int i = 0; i < 4; ++i)
            bf[i] = *reinterpret_cast<const short8*>(BrdB + i * 512);
        #pragma unroll
        for (int i = 0; i < 4; ++i)
            #pragma unroll
            for (int j = 0; j < 4; ++j)
                acc[i][j] = __builtin_amdgcn_mfma_f32_16x16x32_bf16(
                    af[i], bf[j], acc[i][j], 0, 0, 0);
        __syncthreads();
    }

    // epilogue: C/D layout col = l&15, row = (l>>4)*4 + reg
    const int rq = (l >> 4) * 4;
    #pragma unroll
    for (int fn = 0; fn < 4; ++fn) {
        const int col = c0 + wc * 64 + fn * 16 + fr;
        const float bb = bias[col];
        #pragma unroll
        for (int fm = 0; fm < 4; ++fm) {
            const int rbase = m0 + wr * 64 + fm * 16 + rq;
            #pragma unroll
            for (int j = 0; j < 4; ++j) {
                const int r = rbase + j;
                if (r < M) {
                    float v = fmaxf(acc[fm][fn][j] + bb, 0.f);
                    if (WF) outf[(size_t)r * DHID + col] = v;
                    if (WB) outb[(size_t)r * DHID + col] = f2b(v);
                }
            }
        }
    }
}

extern "C" void kernel_launch(void* const* d_in, const int* in_sizes, int n_in,
                              void* d_out, int out_size, void* d_ws, size_t ws_size,
                              hipStream_t stream)
{
    const float* x   = (const float*)d_in[0];
    const int*   ei  = (const int*)d_in[1];
    const int*   src = ei;
    const int*   dst = ei + NE;
    const float* Wl0 = (const float*)d_in[2];
    const float* Wr0 = (const float*)d_in[3];
    const float* b0  = (const float*)d_in[4];
    const float* Wl1 = (const float*)d_in[5];
    const float* Wr1 = (const float*)d_in[6];
    const float* b1  = (const float*)d_in[7];
    float* out = (float*)d_out;

    // workspace layout (bytes):
    //   hist    : @0          400384
    //   offs    : @400384     400640
    //   perm    : @801024     2500352
    //   bsum    : @3301376    4096
    //   bpre    : @3305472    4096
    //   cursor  : @3309568    400384
    //   WT0     : @3709952    131072   (256 x 256 bf16)
    //   WT1     : @3841024    262144   (256 x 512 bf16)
    //   xb      : @4103168    25600000 (100000 x 128 bf16)
    //   h0b     : @29703168   51200000 (100000 x 256 bf16)
    //   aggb    : @80903168   51200000 (100000 x 256 bf16; L0 uses half)
    // total ~132.1 MB (round-0 proved >=256 MB available)
    char* ws = (char*)d_ws;
    int*            hist   = (int*)(ws);
    int*            offs   = (int*)(ws + 400384);
    int*            perm   = (int*)(ws + 801024);
    int*            bsum   = (int*)(ws + 3301376);
    int*            bpre   = (int*)(ws + 3305472);
    int*            cursor = (int*)(ws + 3309568);
    unsigned short* WT0    = (unsigned short*)(ws + 3709952);
    unsigned short* WT1    = (unsigned short*)(ws + 3841024);
    unsigned short* xb     = (unsigned short*)(ws + 4103168);
    unsigned short* h0b    = (unsigned short*)(ws + 29703168);
    unsigned short* aggb   = (unsigned short*)(ws + 80903168);

    zero_kernel<<<(NN + 255) / 256, 256, 0, stream>>>(hist, NN);
    hist_kernel<<<(NE + 255) / 256, 256, 0, stream>>>(dst, hist);
    chunk_sum_kernel<<<NB, 256, 0, stream>>>(hist, bsum);
    scan_bsum_kernel<<<1, 512, 0, stream>>>(bsum, bpre);
    scatter_offs_kernel<<<NB, 256, 0, stream>>>(hist, bpre, offs, cursor);
    perm_kernel<<<(NE + 255) / 256, 256, 0, stream>>>(src, dst, cursor, perm);

    // weight prep + x conversion (independent of CSR)
    prep_w_kernel<DIN ><<<(256 * 2 * DIN  + 255) / 256, 256, 0, stream>>>(Wl0, Wr0, WT0);
    prep_w_kernel<DHID><<<(256 * 2 * DHID + 255) / 256, 256, 0, stream>>>(Wl1, Wr1, WT1);
    convert_kernel<<<(NN * DIN / 8 + 255) / 256, 256, 0, stream>>>(x, xb, NN * DIN / 8);

    constexpr int NWBLK = (NN * 64 + 255) / 256;
    dim3 ggrid((NN + 127) / 128, DHID / 128);

    // ---- layer 0 ----
    gather_mean_kernel<DIN><<<NWBLK, 256, 0, stream>>>(offs, perm, xb, aggb);
    sage_mfma_gemm<DIN, false, true><<<ggrid, 256, 0, stream>>>(
        aggb, xb, WT0, b0, nullptr, h0b, NN);

    // ---- layer 1 ----
    gather_mean_kernel<DHID><<<NWBLK, 256, 0, stream>>>(offs, perm, h0b, aggb);
    sage_mfma_gemm<DHID, true, false><<<ggrid, 256, 0, stream>>>(
        aggb, h0b, WT1, b1, out, nullptr, NN);
}

// Round 7
// 290.795 us; speedup vs baseline: 12.7810x; 1.2119x over previous
//
#include <hip/hip_runtime.h>

// GraphSAGE 2-layer: CSR gather-mean (bf16) + bf16 MFMA fused GEMMs.
// R7: latency-optimized gather (perm preload + readlane broadcast + 4
//     independent load chains); merged convert/prep_w kernels (11 launches).
// Keeps R6 safety: zero_kernel (no memset node), separate cursor, vmcnt fence.

constexpr int NN   = 100000;
constexpr int NE   = 625000;
constexpr int DIN  = 128;
constexpr int DHID = 256;
constexpr int NB   = (NN + 255) / 256;     // 391 scan chunks
constexpr int CONV_BLKS = NN * DIN / 8 / 256;   // 6250 (exact)

using short8 = __attribute__((ext_vector_type(8))) short;
using f32x4  = __attribute__((ext_vector_type(4))) float;

__device__ __forceinline__ float bf2f(unsigned int u) {
    return __uint_as_float(u << 16);
}
__device__ __forceinline__ unsigned short f2b(float f) {
    unsigned int u = __float_as_uint(f);
    unsigned int r = (u + 0x7fffu + ((u >> 16) & 1u)) >> 16;   // RNE
    return (unsigned short)r;
}
__device__ __forceinline__ unsigned int pack2(float lo, float hi) {
    return (unsigned int)f2b(lo) | ((unsigned int)f2b(hi) << 16);
}
__device__ __forceinline__ void gload16(const void* g, void* lds) {
    __builtin_amdgcn_global_load_lds(
        (const __attribute__((address_space(1))) void*)g,
        (__attribute__((address_space(3))) void*)lds, 16, 0, 0);
}

// ---------------- CSR build ------------------------------------------------
__global__ __launch_bounds__(256) void zero_kernel(int* __restrict__ p, int n)
{
    int t = blockIdx.x * 256 + threadIdx.x;
    if (t < n) p[t] = 0;
}

__global__ __launch_bounds__(256) void hist_kernel(const int* __restrict__ dst,
                                                   int* __restrict__ hist)
{
    int t = blockIdx.x * 256 + threadIdx.x;
    if (t < NE) atomicAdd(&hist[dst[t]], 1);
}

__global__ __launch_bounds__(256) void chunk_sum_kernel(const int* __restrict__ hist,
                                                        int* __restrict__ bsum)
{
    __shared__ int s[256];
    int i = blockIdx.x * 256 + threadIdx.x;
    s[threadIdx.x] = (i < NN) ? hist[i] : 0;
    __syncthreads();
    for (int off = 128; off > 0; off >>= 1) {
        if (threadIdx.x < off) s[threadIdx.x] += s[threadIdx.x + off];
        __syncthreads();
    }
    if (threadIdx.x == 0) bsum[blockIdx.x] = s[0];
}

__global__ __launch_bounds__(512) void scan_bsum_kernel(const int* __restrict__ bsum,
                                                        int* __restrict__ bpre)
{
    __shared__ int s[512];
    int t = threadIdx.x;
    int v = (t < NB) ? bsum[t] : 0;
    s[t] = v;
    __syncthreads();
    for (int off = 1; off < 512; off <<= 1) {
        int u = (t >= off) ? s[t - off] : 0;
        __syncthreads();
        s[t] += u;
        __syncthreads();
    }
    if (t < NB) bpre[t] = s[t] - v;        // exclusive prefix
}

__global__ __launch_bounds__(256) void scatter_offs_kernel(const int* __restrict__ hist,
                                                           const int* __restrict__ bpre,
                                                           int* __restrict__ offs,
                                                           int* __restrict__ cursor)
{
    __shared__ int s[256];
    int t = threadIdx.x;
    int i = blockIdx.x * 256 + t;
    int v = (i < NN) ? hist[i] : 0;
    s[t] = v;
    __syncthreads();
    for (int off = 1; off < 256; off <<= 1) {
        int u = (t >= off) ? s[t - off] : 0;
        __syncthreads();
        s[t] += u;
        __syncthreads();
    }
    int excl = s[t] - v + bpre[blockIdx.x];
    if (i < NN) {
        offs[i]   = excl;
        cursor[i] = excl;
    }
    if (i == NN - 1) offs[NN] = NE;
}

__global__ __launch_bounds__(256) void perm_kernel(const int* __restrict__ src,
                                                   const int* __restrict__ dst,
                                                   int* __restrict__ cursor,
                                                   int* __restrict__ perm)
{
    int t = blockIdx.x * 256 + threadIdx.x;
    if (t < NE) {
        int p = atomicAdd(&cursor[dst[t]], 1);
        perm[p] = src[t];
    }
}

// ---------------- merged prep: x->bf16, WT0, WT1 ---------------------------
__global__ __launch_bounds__(256) void prep_all_kernel(
    const float* __restrict__ x, unsigned short* __restrict__ xb,
    const float* __restrict__ Wl0, const float* __restrict__ Wr0,
    unsigned short* __restrict__ WT0,
    const float* __restrict__ Wl1, const float* __restrict__ Wr1,
    unsigned short* __restrict__ WT1)
{
    int b = blockIdx.x;
    if (b < CONV_BLKS) {
        int t = b * 256 + threadIdx.x;          // [0, 1.6M) exact
        float4 v0 = reinterpret_cast<const float4*>(x)[t * 2 + 0];
        float4 v1 = reinterpret_cast<const float4*>(x)[t * 2 + 1];
        uint4 o;
        o.x = pack2(v0.x, v0.y); o.y = pack2(v0.z, v0.w);
        o.z = pack2(v1.x, v1.y); o.w = pack2(v1.z, v1.w);
        reinterpret_cast<uint4*>(xb)[t] = o;
    } else if (b < CONV_BLKS + 256) {
        int t = (b - CONV_BLKS) * 256 + threadIdx.x;   // [0, 65536)
        int n = t >> 8, k = t & 255;
        float v = (k < DIN) ? Wl0[(size_t)k * DHID + n]
                            : Wr0[(size_t)(k - DIN) * DHID + n];
        WT0[t] = f2b(v);
    } else {
        int t = (b - CONV_BLKS - 256) * 256 + threadIdx.x;   // [0, 131072)
        int n = t >> 9, k = t & 511;
        float v = (k < DHID) ? Wl1[(size_t)k * DHID + n]
                             : Wr1[(size_t)(k - DHID) * DHID + n];
        WT1[t] = f2b(v);
    }
}

// ---------------- gather-mean aggregation (latency-optimized) --------------
// One wave per node. perm entries preloaded lane-parallel, broadcast via
// readlane; 4 independent row-load chains to keep >=4 loads in flight.
template <int D>
__global__ __launch_bounds__(256) void gather_mean_kernel(
    const int* __restrict__ offs, const int* __restrict__ perm,
    const unsigned short* __restrict__ feat, unsigned short* __restrict__ agg)
{
    const int w    = (blockIdx.x * 256 + threadIdx.x) >> 6;
    const int lane = threadIdx.x & 63;
    if (w >= NN) return;
    const int beg = offs[w], end = offs[w + 1];
    const int deg = end - beg;
    const float sc = 1.0f / (float)(deg > 1 ? deg : 1);

    if constexpr (D == 256) {
        const uint2* base = reinterpret_cast<const uint2*>(feat);
        float a0[4] = {}, a1[4] = {}, a2[4] = {}, a3[4] = {};
        for (int e0 = 0; e0 < deg; e0 += 64) {
            const int chunk = min(deg - e0, 64);
            int pv = (lane < chunk) ? perm[beg + e0 + lane] : 0;
            int i = chunk & 3;
            // remainder first, independent chains
            if (i > 0) {
                int s = __builtin_amdgcn_readlane(pv, 0);
                uint2 v = base[(size_t)s * 64 + lane];
                a1[0] += bf2f(v.x & 0xffffu); a1[1] += bf2f(v.x >> 16);
                a1[2] += bf2f(v.y & 0xffffu); a1[3] += bf2f(v.y >> 16);
            }
            if (i > 1) {
                int s = __builtin_amdgcn_readlane(pv, 1);
                uint2 v = base[(size_t)s * 64 + lane];
                a2[0] += bf2f(v.x & 0xffffu); a2[1] += bf2f(v.x >> 16);
                a2[2] += bf2f(v.y & 0xffffu); a2[3] += bf2f(v.y >> 16);
            }
            if (i > 2) {
                int s = __builtin_amdgcn_readlane(pv, 2);
                uint2 v = base[(size_t)s * 64 + lane];
                a3[0] += bf2f(v.x & 0xffffu); a3[1] += bf2f(v.x >> 16);
                a3[2] += bf2f(v.y & 0xffffu); a3[3] += bf2f(v.y >> 16);
            }
            for (; i + 4 <= chunk; i += 4) {
                int s0 = __builtin_amdgcn_readlane(pv, i + 0);
                int s1 = __builtin_amdgcn_readlane(pv, i + 1);
                int s2 = __builtin_amdgcn_readlane(pv, i + 2);
                int s3 = __builtin_amdgcn_readlane(pv, i + 3);
                uint2 v0 = base[(size_t)s0 * 64 + lane];
                uint2 v1 = base[(size_t)s1 * 64 + lane];
                uint2 v2 = base[(size_t)s2 * 64 + lane];
                uint2 v3 = base[(size_t)s3 * 64 + lane];
                a0[0] += bf2f(v0.x & 0xffffu); a0[1] += bf2f(v0.x >> 16);
                a0[2] += bf2f(v0.y & 0xffffu); a0[3] += bf2f(v0.y >> 16);
                a1[0] += bf2f(v1.x & 0xffffu); a1[1] += bf2f(v1.x >> 16);
                a1[2] += bf2f(v1.y & 0xffffu); a1[3] += bf2f(v1.y >> 16);
                a2[0] += bf2f(v2.x & 0xffffu); a2[1] += bf2f(v2.x >> 16);
                a2[2] += bf2f(v2.y & 0xffffu); a2[3] += bf2f(v2.y >> 16);
                a3[0] += bf2f(v3.x & 0xffffu); a3[1] += bf2f(v3.x >> 16);
                a3[2] += bf2f(v3.y & 0xffffu); a3[3] += bf2f(v3.y >> 16);
            }
        }
        float r0 = (a0[0] + a1[0]) + (a2[0] + a3[0]);
        float r1 = (a0[1] + a1[1]) + (a2[1] + a3[1]);
        float r2 = (a0[2] + a1[2]) + (a2[2] + a3[2]);
        float r3 = (a0[3] + a1[3]) + (a2[3] + a3[3]);
        uint2 o;
        o.x = pack2(r0 * sc, r1 * sc);
        o.y = pack2(r2 * sc, r3 * sc);
        reinterpret_cast<uint2*>(agg)[(size_t)w * 64 + lane] = o;
    } else {   // D == 128: row = 64 uints (4B/lane)
        const unsigned int* base = reinterpret_cast<const unsigned int*>(feat);
        float a0[2] = {}, a1[2] = {}, a2[2] = {}, a3[2] = {};
        for (int e0 = 0; e0 < deg; e0 += 64) {
            const int chunk = min(deg - e0, 64);
            int pv = (lane < chunk) ? perm[beg + e0 + lane] : 0;
            int i = chunk & 3;
            if (i > 0) {
                int s = __builtin_amdgcn_readlane(pv, 0);
                unsigned int v = base[(size_t)s * 64 + lane];
                a1[0] += bf2f(v & 0xffffu); a1[1] += bf2f(v >> 16);
            }
            if (i > 1) {
                int s = __builtin_amdgcn_readlane(pv, 1);
                unsigned int v = base[(size_t)s * 64 + lane];
                a2[0] += bf2f(v & 0xffffu); a2[1] += bf2f(v >> 16);
            }
            if (i > 2) {
                int s = __builtin_amdgcn_readlane(pv, 2);
                unsigned int v = base[(size_t)s * 64 + lane];
                a3[0] += bf2f(v & 0xffffu); a3[1] += bf2f(v >> 16);
            }
            for (; i + 4 <= chunk; i += 4) {
                int s0 = __builtin_amdgcn_readlane(pv, i + 0);
                int s1 = __builtin_amdgcn_readlane(pv, i + 1);
                int s2 = __builtin_amdgcn_readlane(pv, i + 2);
                int s3 = __builtin_amdgcn_readlane(pv, i + 3);
                unsigned int v0 = base[(size_t)s0 * 64 + lane];
                unsigned int v1 = base[(size_t)s1 * 64 + lane];
                unsigned int v2 = base[(size_t)s2 * 64 + lane];
                unsigned int v3 = base[(size_t)s3 * 64 + lane];
                a0[0] += bf2f(v0 & 0xffffu); a0[1] += bf2f(v0 >> 16);
                a1[0] += bf2f(v1 & 0xffffu); a1[1] += bf2f(v1 >> 16);
                a2[0] += bf2f(v2 & 0xffffu); a2[1] += bf2f(v2 >> 16);
                a3[0] += bf2f(v3 & 0xffffu); a3[1] += bf2f(v3 >> 16);
            }
        }
        float r0 = (a0[0] + a1[0]) + (a2[0] + a3[0]);
        float r1 = (a0[1] + a1[1]) + (a2[1] + a3[1]);
        reinterpret_cast<unsigned int*>(agg)[(size_t)w * 64 + lane] = pack2(r0 * sc, r1 * sc);
    }
}

// ---------------- bf16 MFMA fused SAGE GEMM --------------------------------
// out[m,c] = relu( [agg | xr][m,:] @ WT^T + bias ),  WT is [256][2KP] bf16.
// 128x128 tile, 4 waves (2x2 of 64x64), BK=32, 16x16x32 MFMA.
// LDS swizzle: chunk c16' = c16 ^ (row&3), on BOTH gload source and ds_read.
template <int KP, bool WF, bool WB>
__global__ __launch_bounds__(256) void sage_mfma_gemm(
    const unsigned short* __restrict__ Aagg,  // [M, KP] bf16
    const unsigned short* __restrict__ Axr,   // [M, KP] bf16
    const unsigned short* __restrict__ WT,    // [256, 2KP] bf16
    const float* __restrict__ bias,
    float* __restrict__ outf,                 // used if WF
    unsigned short* __restrict__ outb,        // used if WB
    int M)
{
    __shared__ __align__(16) unsigned short As[128 * 32];
    __shared__ __align__(16) unsigned short Bs[128 * 32];

    const int t   = threadIdx.x;
    const int l   = t & 63;
    const int wid = t >> 6;
    const int wr  = wid >> 1, wc = wid & 1;
    const int m0  = blockIdx.x * 128;
    const int c0  = blockIdx.y * 128;

    const int rin = l >> 2;                  // row within chunk
    const int p   = l & 3;                   // physical 16B slot in row
    const int csw = p ^ (rin & 3);           // swizzled source chunk
    const int ch0 = wid * 2, ch1 = ch0 + 1;

    int arow0 = m0 + ch0 * 16 + rin; if (arow0 >= M) arow0 = M - 1;
    int arow1 = m0 + ch1 * 16 + rin; if (arow1 >= M) arow1 = M - 1;
    const int brow0 = c0 + ch0 * 16 + rin;
    const int brow1 = c0 + ch1 * 16 + rin;

    unsigned short* AsD0 = As + ch0 * 512;   // wave-uniform LDS dest
    unsigned short* AsD1 = As + ch1 * 512;
    unsigned short* BsD0 = Bs + ch0 * 512;
    unsigned short* BsD1 = Bs + ch1 * 512;

    const int fr  = l & 15;
    const int swz = ((l >> 4) ^ (l & 3)) * 8;           // ushort units
    const unsigned short* ArdB = As + (wr * 64 + fr) * 32 + swz;
    const unsigned short* BrdB = Bs + (wc * 64 + fr) * 32 + swz;

    f32x4 acc[4][4] = {};

    constexpr int K2 = 2 * KP;
    constexpr int KT = K2 / 32;
    for (int kt = 0; kt < KT; ++kt) {
        const int kb = kt * 32;
        const unsigned short* Asrc;
        int kk;
        if (kb < KP) { Asrc = Aagg; kk = kb; }
        else         { Asrc = Axr;  kk = kb - KP; }
        gload16(Asrc + (size_t)arow0 * KP + kk + csw * 8, AsD0);
        gload16(Asrc + (size_t)arow1 * KP + kk + csw * 8, AsD1);
        gload16(WT + (size_t)brow0 * K2 + kb + csw * 8, BsD0);
        gload16(WT + (size_t)brow1 * K2 + kb + csw * 8, BsD1);
        asm volatile("s_waitcnt vmcnt(0)" ::: "memory");  // explicit drain
        __syncthreads();

        short8 af[4], bf[4];
        #pragma unroll
        for (int i = 0; i < 4; ++i)
            af[i] = *reinterpret_cast<const short8*>(ArdB + i * 512);
        #pragma unroll
        for (int i = 0; i < 4; ++i)
            bf[i] = *reinterpret_cast<const short8*>(BrdB + i * 512);
        #pragma unroll
        for (int i = 0; i < 4; ++i)
            #pragma unroll
            for (int j = 0; j < 4; ++j)
                acc[i][j] = __builtin_amdgcn_mfma_f32_16x16x32_bf16(
                    af[i], bf[j], acc[i][j], 0, 0, 0);
        __syncthreads();
    }

    // epilogue: C/D layout col = l&15, row = (l>>4)*4 + reg
    const int rq = (l >> 4) * 4;
    #pragma unroll
    for (int fn = 0; fn < 4; ++fn) {
        const int col = c0 + wc * 64 + fn * 16 + fr;
        const float bb = bias[col];
        #pragma unroll
        for (int fm = 0; fm < 4; ++fm) {
            const int rbase = m0 + wr * 64 + fm * 16 + rq;
            #pragma unroll
            for (int j = 0; j < 4; ++j) {
                const int r = rbase + j;
                if (r < M) {
                    float v = fmaxf(acc[fm][fn][j] + bb, 0.f);
                    if (WF) outf[(size_t)r * DHID + col] = v;
                    if (WB) outb[(size_t)r * DHID + col] = f2b(v);
                }
            }
        }
    }
}

extern "C" void kernel_launch(void* const* d_in, const int* in_sizes, int n_in,
                              void* d_out, int out_size, void* d_ws, size_t ws_size,
                              hipStream_t stream)
{
    const float* x   = (const float*)d_in[0];
    const int*   ei  = (const int*)d_in[1];
    const int*   src = ei;
    const int*   dst = ei + NE;
    const float* Wl0 = (const float*)d_in[2];
    const float* Wr0 = (const float*)d_in[3];
    const float* b0  = (const float*)d_in[4];
    const float* Wl1 = (const float*)d_in[5];
    const float* Wr1 = (const float*)d_in[6];
    const float* b1  = (const float*)d_in[7];
    float* out = (float*)d_out;

    // workspace layout (bytes):
    //   hist    : @0          400384
    //   offs    : @400384     400640
    //   perm    : @801024     2500352
    //   bsum    : @3301376    4096
    //   bpre    : @3305472    4096
    //   cursor  : @3309568    400384
    //   WT0     : @3709952    131072
    //   WT1     : @3841024    262144
    //   xb      : @4103168    25600000
    //   h0b     : @29703168   51200000
    //   aggb    : @80903168   51200000
    // total ~132.1 MB
    char* ws = (char*)d_ws;
    int*            hist   = (int*)(ws);
    int*            offs   = (int*)(ws + 400384);
    int*            perm   = (int*)(ws + 801024);
    int*            bsum   = (int*)(ws + 3301376);
    int*            bpre   = (int*)(ws + 3305472);
    int*            cursor = (int*)(ws + 3309568);
    unsigned short* WT0    = (unsigned short*)(ws + 3709952);
    unsigned short* WT1    = (unsigned short*)(ws + 3841024);
    unsigned short* xb     = (unsigned short*)(ws + 4103168);
    unsigned short* h0b    = (unsigned short*)(ws + 29703168);
    unsigned short* aggb   = (unsigned short*)(ws + 80903168);

    zero_kernel<<<(NN + 255) / 256, 256, 0, stream>>>(hist, NN);
    hist_kernel<<<(NE + 255) / 256, 256, 0, stream>>>(dst, hist);
    chunk_sum_kernel<<<NB, 256, 0, stream>>>(hist, bsum);
    scan_bsum_kernel<<<1, 512, 0, stream>>>(bsum, bpre);
    scatter_offs_kernel<<<NB, 256, 0, stream>>>(hist, bpre, offs, cursor);
    perm_kernel<<<(NE + 255) / 256, 256, 0, stream>>>(src, dst, cursor, perm);

    prep_all_kernel<<<CONV_BLKS + 256 + 512, 256, 0, stream>>>(
        x, xb, Wl0, Wr0, WT0, Wl1, Wr1, WT1);

    constexpr int NWBLK = (NN * 64) / 256;   // 25000 exactly
    dim3 ggrid((NN + 127) / 128, DHID / 128);

    // ---- layer 0 ----
    gather_mean_kernel<DIN><<<NWBLK, 256, 0, stream>>>(offs, perm, xb, aggb);
    sage_mfma_gemm<DIN, false, true><<<ggrid, 256, 0, stream>>>(
        aggb, xb, WT0, b0, nullptr, h0b, NN);

    // ---- layer 1 ----
    gather_mean_kernel<DHID><<<NWBLK, 256, 0, stream>>>(offs, perm, h0b, aggb);
    sage_mfma_gemm<DHID, true, false><<<ggrid, 256, 0, stream>>>(
        aggb, h0b, WT1, b1, out, nullptr, NN);
}